// Round 1
// baseline (18002.164 us; speedup 1.0000x reference)
//
#include <hip/hip_runtime.h>
#include <math.h>

#define BB 8
#define TT 1024
#define HDIM 1024
#define G3 3072  // 3*H

// conv-gates GEMM: x [B,T,C], w [3H,C,3], bias [3H] -> g (activated) [B,T,3H]
// g[b,t,j] = act( bias[j] + sum_{c,k} w[j,c,k] * x[b, t+k-1, c] ), zero-pad in t.
template<int C>
__global__ __launch_bounds__(256) void conv_gates_kernel(
    const float* __restrict__ x, const float* __restrict__ w,
    const float* __restrict__ bias, float* __restrict__ g)
{
  // grid: (T/64, 3H/64, B); block 256 = 16x16, each thread 4x4 outputs
  const int t0 = blockIdx.x * 64;
  const int j0 = blockIdx.y * 64;
  const int b  = blockIdx.z;
  const int tid = threadIdx.x;
  const int tx = tid & 15;   // j direction (4 consecutive j per thread)
  const int ty = tid >> 4;   // t direction (4 consecutive t per thread)

  // xs rows padded to 17 floats: a-frag rows differ by 4 -> banks spread 0/4/8/12
  __shared__ float xs[66][17];
  // wsh rows padded to 49: b-frag rows differ by 4*49=196 -> 2-way alias (free)
  __shared__ float wsh[64][49];  // [j_local][c_local*3 + k]

  float acc[4][4];
  #pragma unroll
  for (int i = 0; i < 4; i++)
    #pragma unroll
    for (int u = 0; u < 4; u++) acc[i][u] = 0.f;

  const float* xb = x + (size_t)b * TT * C;

  for (int c0 = 0; c0 < C; c0 += 16) {
    // stage x tile: rows t0-1 .. t0+64 (66 rows) x 16 c, zero-padded
    for (int e = tid; e < 66 * 16; e += 256) {
      int r = e >> 4, cc = e & 15;
      int tg = t0 + r - 1;
      float v = 0.f;
      if (tg >= 0 && tg < TT) v = xb[(size_t)tg * C + (c0 + cc)];
      xs[r][cc] = v;
    }
    // stage w tile: 64 j x 48 (c-major, k inner) -- 48-float contiguous runs in global
    for (int e = tid; e < 64 * 48; e += 256) {
      int j = e / 48, q = e % 48;
      wsh[j][q] = w[(size_t)(j0 + j) * (C * 3) + (size_t)c0 * 3 + q];
    }
    __syncthreads();

    #pragma unroll 4
    for (int c = 0; c < 16; ++c) {
      float a[6];
      #pragma unroll
      for (int i = 0; i < 6; i++) a[i] = xs[ty * 4 + i][c];
      #pragma unroll
      for (int k = 0; k < 3; k++) {
        float bv[4];
        #pragma unroll
        for (int u = 0; u < 4; u++) bv[u] = wsh[tx * 4 + u][c * 3 + k];
        #pragma unroll
        for (int i = 0; i < 4; i++)
          #pragma unroll
          for (int u = 0; u < 4; u++)
            acc[i][u] = fmaf(a[i + k], bv[u], acc[i][u]);
      }
    }
    __syncthreads();
  }

  // epilogue: bias + activation, float4 store (4 consecutive j per thread)
  const int jbase = j0 + tx * 4;
  float bb[4];
  #pragma unroll
  for (int u = 0; u < 4; u++) bb[u] = bias[jbase + u];
  const bool is_tanh = (jbase >= 2 * HDIM);  // j-tiles never straddle gate boundary
  #pragma unroll
  for (int i = 0; i < 4; i++) {
    int t = t0 + ty * 4 + i;
    float4 v;
    float* vp = &v.x;
    #pragma unroll
    for (int u = 0; u < 4; u++) {
      float s = acc[i][u] + bb[u];
      vp[u] = is_tanh ? tanhf(s) : (1.f / (1.f + expf(-s)));
    }
    *(float4*)(g + ((size_t)b * TT + t) * G3 + jbase) = v;
  }
}

// fo-pool: c_t = f*c_{t-1} + (1-f)*z ; h = c*o. dir=0 fwd, dir=1 scans t backwards.
// Writes h into out[b, t, dir*H + h]; records h,c at original t==T-1 into hid/cell.
__global__ __launch_bounds__(256) void fo_pool_kernel(
    const float* __restrict__ g,   // [B,T,3H] activated (f,o,z)
    float* __restrict__ out,       // [B,T,2H]
    float* __restrict__ hid,       // [4,B,H] flat section
    float* __restrict__ cell,      // [4,B,H] flat section
    int dir, int layer)
{
  int idx = blockIdx.x * 256 + threadIdx.x;  // 0 .. B*H-1
  int b = idx >> 10;
  int h = idx & (HDIM - 1);
  const float* gb = g + (size_t)b * TT * G3 + h;
  const int coloff = dir * HDIM;
  float* ob = out + (size_t)b * TT * (2 * HDIM) + coloff + h;
  float c = 0.f;
  for (int s = 0; s < TT; ++s) {
    int t = dir ? (TT - 1 - s) : s;
    size_t go = (size_t)t * G3;
    float f = gb[go];
    float o = gb[go + HDIM];
    float z = gb[go + 2 * HDIM];
    c = f * c + (1.f - f) * z;
    float hv = c * o;
    ob[(size_t)t * (2 * HDIM)] = hv;
    if (t == TT - 1) {  // fwd: last step; rev: first step (rcells[:,-1])
      size_t off = (size_t)layer * (BB * 2 * HDIM) + (size_t)b * (2 * HDIM) + coloff + h;
      hid[off] = hv;
      cell[off] = c;
    }
  }
}

extern "C" void kernel_launch(void* const* d_in, const int* in_sizes, int n_in,
                              void* d_out, int out_size, void* d_ws, size_t ws_size,
                              hipStream_t stream) {
  const float* x   = (const float*)d_in[0];
  // d_in[1] = lengths (all == T, unused)
  const float* w0f = (const float*)d_in[2];
  const float* b0f = (const float*)d_in[3];
  const float* w0r = (const float*)d_in[4];
  const float* b0r = (const float*)d_in[5];
  const float* w1f = (const float*)d_in[6];
  const float* b1f = (const float*)d_in[7];
  const float* w1r = (const float*)d_in[8];
  const float* b1r = (const float*)d_in[9];

  float* out1 = (float*)d_out;                          // B*T*2H
  float* hid  = out1 + (size_t)BB * TT * 2 * HDIM;      // 4*B*H
  float* cell = hid + 4 * BB * HDIM;                    // 4*B*H

  float* g    = (float*)d_ws;                           // B*T*3H   (100.7 MB)
  float* out0 = g + (size_t)BB * TT * G3;               // B*T*2H   (67.1 MB)

  dim3 blk(256);
  dim3 grd(TT / 64, G3 / 64, BB);
  dim3 pgrd(BB * HDIM / 256);

  // layer 0 (input x, C=1024)
  conv_gates_kernel<1024><<<grd, blk, 0, stream>>>(x, w0f, b0f, g);
  fo_pool_kernel<<<pgrd, blk, 0, stream>>>(g, out0, hid, cell, 0, 0);
  conv_gates_kernel<1024><<<grd, blk, 0, stream>>>(x, w0r, b0r, g);
  fo_pool_kernel<<<pgrd, blk, 0, stream>>>(g, out0, hid, cell, 1, 0);

  // layer 1 (input out0, C=2048)
  conv_gates_kernel<2048><<<grd, blk, 0, stream>>>(out0, w1f, b1f, g);
  fo_pool_kernel<<<pgrd, blk, 0, stream>>>(g, out1, hid, cell, 0, 1);
  conv_gates_kernel<2048><<<grd, blk, 0, stream>>>(out0, w1r, b1r, g);
  fo_pool_kernel<<<pgrd, blk, 0, stream>>>(g, out1, hid, cell, 1, 1);
}

// Round 2
// 2729.240 us; speedup vs baseline: 6.5960x; 6.5960x over previous
//
#include <hip/hip_runtime.h>
#include <math.h>

#define BB 8
#define TT 1024
#define HDIM 1024
#define G3 3072  // 3*H

typedef __attribute__((ext_vector_type(8))) short bf16x8;   // 8 bf16 = 4 VGPRs
typedef __attribute__((ext_vector_type(4))) float f32x4;

__device__ __forceinline__ unsigned short f2bf(float f) {
  union { float f; unsigned int u; } c; c.f = f;
  unsigned int u = c.u;
  return (unsigned short)((u + 0x7FFFu + ((u >> 16) & 1u)) >> 16);
}

__device__ __forceinline__ void load_lds16(const void* g, void* l) {
  __builtin_amdgcn_global_load_lds(
      (const __attribute__((address_space(1))) void*)g,
      (__attribute__((address_space(3))) void*)l, 16, 0, 0);
}

// x [B,T,D] fp32 -> bf16
__global__ __launch_bounds__(256) void cvt_x_kernel(const float* __restrict__ in,
                                                    unsigned short* __restrict__ out, int n) {
  int i = (blockIdx.x * 256 + threadIdx.x) * 4;
  if (i >= n) return;
  float4 v = *(const float4*)(in + i);
  ushort4 o;
  o.x = f2bf(v.x); o.y = f2bf(v.y); o.z = f2bf(v.z); o.w = f2bf(v.w);
  *(ushort4*)(out + i) = o;
}

// w [3H, C, 3] fp32 -> wt [3][3H][C] bf16
template<int C>
__global__ __launch_bounds__(256) void cvt_w_kernel(const float* __restrict__ in,
                                                    unsigned short* __restrict__ out) {
  int o = blockIdx.x * 256 + threadIdx.x;  // 3*3072*C total
  int c = o & (C - 1);
  int jk = o / C;
  int j = jk & (G3 - 1);     // G3=3072 not pow2 -- do it properly below
  j = jk % G3;
  int k = jk / G3;
  out[o] = f2bf(in[(size_t)j * (3 * C) + (size_t)c * 3 + k]);
}

// conv-gates via bf16 MFMA: g[b,t,j] = act(bias[j] + sum_{k,c} wt[k][j][c]*x[b,t+k-1,c])
// Block: 128(t) x 128(j), BK=32. 4 waves, each 64x64 via 4x4 mfma 16x16x32.
template<int C>
__global__ __launch_bounds__(256) void conv_mfma_kernel(
    const unsigned short* __restrict__ x,   // [B,T,C] bf16
    const unsigned short* __restrict__ wt,  // [3][3072][C] bf16
    const float* __restrict__ bias,         // [3072]
    float* __restrict__ g)                  // [B,T,3072]
{
  const int t0 = blockIdx.x * 128;
  const int j0 = blockIdx.y * 128;
  const int b  = blockIdx.z;
  const int tid  = threadIdx.x;
  const int lane = tid & 63;
  const int wave = tid >> 6;
  const int wm = wave >> 1, wn = wave & 1;

  __shared__ unsigned short As[130 * 32];      // rows t0-1..t0+128, 64B rows
  __shared__ unsigned short Bs[3 * 128 * 32];  // [k][j_local][c], 64B rows

  f32x4 acc[4][4];
  #pragma unroll
  for (int i = 0; i < 4; i++)
    #pragma unroll
    for (int u = 0; u < 4; u++) acc[i][u] = (f32x4){0.f, 0.f, 0.f, 0.f};

  const unsigned short* xb = x + (size_t)b * TT * C;
  const int srow  = lane >> 2;   // row within a 16-row staging call
  const int sslot = lane & 3;    // 16B slot within 64B row
  const int rq = lane >> 4;      // frag chunk (8 bf16)
  const int rl = lane & 15;      // frag row

  for (int c0 = 0; c0 < C; c0 += 32) {
    __syncthreads();
    // ---- stage A rows 1..128 (t = t0 .. t0+127): 2 calls per wave, 16 rows each
    #pragma unroll
    for (int cc = 0; cc < 2; ++cc) {
      int lrow0 = 1 + wave * 32 + cc * 16;
      int lrow  = lrow0 + srow;
      int t = t0 + lrow - 1;
      int q = sslot ^ (lrow & 3);  // XOR-swizzled source chunk
      load_lds16(xb + (size_t)t * C + c0 + q * 8, &As[lrow0 * 32]);
    }
    // ---- stage B: 3 shifts x 128 rows = 384 rows: 6 calls per wave
    #pragma unroll
    for (int cc = 0; cc < 6; ++cc) {
      int R0 = (wave * 6 + cc) * 16;
      int R  = R0 + srow;
      int k = R >> 7;
      int j = R & 127;
      int q = sslot ^ (R & 3);
      load_lds16(wt + (size_t)k * (G3 * C) + (size_t)(j0 + j) * C + c0 + q * 8,
                 &Bs[R0 * 32]);
    }
    // ---- boundary rows lrow 0 (t0-1) and 129 (t0+128), zero-padded
    if (tid < 8) {
      int lr = (tid < 4) ? 0 : 129;
      int s  = tid & 3;
      int t  = t0 + lr - 1;
      int q  = s ^ (lr & 3);
      uint4 v = make_uint4(0, 0, 0, 0);
      if (t >= 0 && t < TT) v = *(const uint4*)(xb + (size_t)t * C + c0 + q * 8);
      *(uint4*)&As[lr * 32 + s * 8] = v;
    }
    __syncthreads();

    // ---- compute: 3 conv taps x 16 MFMA
    #pragma unroll
    for (int k = 0; k < 3; ++k) {
      bf16x8 af[4], bfr[4];
      #pragma unroll
      for (int im = 0; im < 4; ++im) {
        int lrow = wm * 64 + im * 16 + rl + k;
        af[im] = *(const bf16x8*)&As[lrow * 32 + ((rq ^ (lrow & 3)) * 8)];
      }
      #pragma unroll
      for (int in = 0; in < 4; ++in) {
        int R = k * 128 + wn * 64 + in * 16 + rl;
        bfr[in] = *(const bf16x8*)&Bs[R * 32 + ((rq ^ (R & 3)) * 8)];
      }
      #pragma unroll
      for (int im = 0; im < 4; ++im)
        #pragma unroll
        for (int in = 0; in < 4; ++in)
          acc[im][in] = __builtin_amdgcn_mfma_f32_16x16x32_bf16(
              af[im], bfr[in], acc[im][in], 0, 0, 0);
    }
  }

  // ---- epilogue: bias + activation, scalar stores (C/D: col=lane&15, row=quad*4+reg)
  const bool is_tanh = (j0 >= 2 * HDIM);  // j-tile never straddles a gate boundary
  const int row_in_tile = (lane >> 4) * 4;
  float* gb = g + (size_t)b * TT * G3;
  #pragma unroll
  for (int in = 0; in < 4; ++in) {
    int j = j0 + wn * 64 + in * 16 + rl;
    float bv = bias[j];
    #pragma unroll
    for (int im = 0; im < 4; ++im) {
      int tl = wm * 64 + im * 16 + row_in_tile;
      #pragma unroll
      for (int r = 0; r < 4; ++r) {
        float s = acc[im][in][r] + bv;
        float v;
        if (is_tanh) v = 1.f - 2.f / (__expf(2.f * s) + 1.f);
        else         v = 1.f / (1.f + __expf(-s));
        gb[(size_t)(t0 + tl + r) * G3 + j] = v;
      }
    }
  }
}

// fo-pool: c_t = f*c_{t-1} + (1-f)*z ; h = c*o. dir=1 scans t backwards.
// OUT_BF16: write h as bf16 (layer0 -> out0), else fp32 (layer1 -> d_out).
template<int OUT_BF16>
__global__ __launch_bounds__(256) void fo_pool_kernel(
    const float* __restrict__ g, void* __restrict__ out,
    float* __restrict__ hid, float* __restrict__ cell, int dir, int layer)
{
  int idx = blockIdx.x * 256 + threadIdx.x;  // 0 .. B*H-1
  int b = idx >> 10;
  int h = idx & (HDIM - 1);
  const float* gb = g + (size_t)b * TT * G3 + h;
  const int coloff = dir * HDIM;
  float c = 0.f;
  for (int s = 0; s < TT; ++s) {
    int t = dir ? (TT - 1 - s) : s;
    size_t go = (size_t)t * G3;
    float f = gb[go];
    float o = gb[go + HDIM];
    float z = gb[go + 2 * HDIM];
    c = f * c + (1.f - f) * z;
    float hv = c * o;
    size_t oo = ((size_t)b * TT + t) * (2 * HDIM) + coloff + h;
    if (OUT_BF16) ((unsigned short*)out)[oo] = f2bf(hv);
    else          ((float*)out)[oo] = hv;
    if (t == TT - 1) {
      size_t off = (size_t)layer * (BB * 2 * HDIM) + (size_t)b * (2 * HDIM) + coloff + h;
      hid[off] = hv;
      cell[off] = c;
    }
  }
}

extern "C" void kernel_launch(void* const* d_in, const int* in_sizes, int n_in,
                              void* d_out, int out_size, void* d_ws, size_t ws_size,
                              hipStream_t stream) {
  const float* x   = (const float*)d_in[0];
  const float* w0f = (const float*)d_in[2];
  const float* b0f = (const float*)d_in[3];
  const float* w0r = (const float*)d_in[4];
  const float* b0r = (const float*)d_in[5];
  const float* w1f = (const float*)d_in[6];
  const float* b1f = (const float*)d_in[7];
  const float* w1r = (const float*)d_in[8];
  const float* b1r = (const float*)d_in[9];

  float* out1 = (float*)d_out;                       // B*T*2H fp32
  float* hid  = out1 + (size_t)BB * TT * 2 * HDIM;   // 4*B*H
  float* cell = hid + 4 * BB * HDIM;                 // 4*B*H

  // workspace layout (byte offsets, all 16B aligned)
  char* ws = (char*)d_ws;
  float*          g     = (float*)ws;                                   // 100.7 MB
  unsigned short* out0b = (unsigned short*)(ws + 100663296);            // 33.6 MB
  unsigned short* xb16  = (unsigned short*)(ws + 100663296 + 33554432); // 16.8 MB
  unsigned short* wt    = (unsigned short*)(ws + 100663296 + 33554432 + 16777216); // 37.75 MB

  dim3 blk(256);
  dim3 cgrd(TT / 128, G3 / 128, BB);   // (8, 24, 8)
  dim3 pgrd(BB * HDIM / 256);          // 32

  // x -> bf16
  int nx = BB * TT * 1024;
  cvt_x_kernel<<<nx / (256 * 4), blk, 0, stream>>>(x, xb16, nx);

  // ---- layer 0 (C=1024)
  cvt_w_kernel<1024><<<3 * G3 * 1024 / 256, blk, 0, stream>>>(w0f, wt);
  conv_mfma_kernel<1024><<<cgrd, blk, 0, stream>>>(xb16, wt, b0f, g);
  fo_pool_kernel<1><<<pgrd, blk, 0, stream>>>(g, out0b, hid, cell, 0, 0);

  cvt_w_kernel<1024><<<3 * G3 * 1024 / 256, blk, 0, stream>>>(w0r, wt);
  conv_mfma_kernel<1024><<<cgrd, blk, 0, stream>>>(xb16, wt, b0r, g);
  fo_pool_kernel<1><<<pgrd, blk, 0, stream>>>(g, out0b, hid, cell, 1, 0);

  // ---- layer 1 (C=2048)
  cvt_w_kernel<2048><<<3 * G3 * 2048 / 256, blk, 0, stream>>>(w1f, wt);
  conv_mfma_kernel<2048><<<cgrd, blk, 0, stream>>>(out0b, wt, b1f, g);
  fo_pool_kernel<0><<<pgrd, blk, 0, stream>>>(g, out1, hid, cell, 0, 1);

  cvt_w_kernel<2048><<<3 * G3 * 2048 / 256, blk, 0, stream>>>(w1r, wt);
  conv_mfma_kernel<2048><<<cgrd, blk, 0, stream>>>(out0b, wt, b1r, g);
  fo_pool_kernel<0><<<pgrd, blk, 0, stream>>>(g, out1, hid, cell, 1, 1);
}

// Round 3
// 1470.062 us; speedup vs baseline: 12.2459x; 1.8565x over previous
//
#include <hip/hip_runtime.h>
#include <math.h>

#define BB 8
#define TT 1024
#define HDIM 1024
#define G3 3072   // 3*H
#define NCH 32    // scan chunks
#define TC 32     // steps per chunk (NCH*TC == TT)

typedef __attribute__((ext_vector_type(8))) short bf16x8;   // 8 bf16 = 4 VGPRs
typedef __attribute__((ext_vector_type(4))) float f32x4;

__device__ __forceinline__ unsigned short f2bf(float f) {
  union { float f; unsigned int u; } c; c.f = f;
  unsigned int u = c.u;
  return (unsigned short)((u + 0x7FFFu + ((u >> 16) & 1u)) >> 16);
}

__device__ __forceinline__ void load_lds16(const void* g, void* l) {
  __builtin_amdgcn_global_load_lds(
      (const __attribute__((address_space(1))) void*)g,
      (__attribute__((address_space(3))) void*)l, 16, 0, 0);
}

// x [B,T,D] fp32 -> bf16
__global__ __launch_bounds__(256) void cvt_x_kernel(const float* __restrict__ in,
                                                    unsigned short* __restrict__ out, int n) {
  int i = (blockIdx.x * 256 + threadIdx.x) * 4;
  if (i >= n) return;
  float4 v = *(const float4*)(in + i);
  ushort4 o;
  o.x = f2bf(v.x); o.y = f2bf(v.y); o.z = f2bf(v.z); o.w = f2bf(v.w);
  *(ushort4*)(out + i) = o;
}

// w [3H, C, 3] fp32 -> wt [3][3H][C] bf16
template<int C>
__global__ __launch_bounds__(256) void cvt_w_kernel(const float* __restrict__ in,
                                                    unsigned short* __restrict__ out) {
  int o = blockIdx.x * 256 + threadIdx.x;  // 3*3072*C total
  int c = o & (C - 1);
  int jk = o / C;
  int j = jk % G3;
  int k = jk / G3;
  out[o] = f2bf(in[(size_t)j * (3 * C) + (size_t)c * 3 + k]);
}

// conv-gates via bf16 MFMA: g[b,t,j] = act(bias[j] + sum_{k,c} wt[k][j][c]*x[b,t+k-1,c])
// Block: 128(t) x 128(j), BK=32. 4 waves, each 64x64 via 4x4 mfma 16x16x32.
template<int C>
__global__ __launch_bounds__(256) void conv_mfma_kernel(
    const unsigned short* __restrict__ x,   // [B,T,C] bf16
    const unsigned short* __restrict__ wt,  // [3][3072][C] bf16
    const float* __restrict__ bias,         // [3072]
    float* __restrict__ g)                  // [B,T,3072]
{
  const int t0 = blockIdx.x * 128;
  const int j0 = blockIdx.y * 128;
  const int b  = blockIdx.z;
  const int tid  = threadIdx.x;
  const int lane = tid & 63;
  const int wave = tid >> 6;
  const int wm = wave >> 1, wn = wave & 1;

  __shared__ unsigned short As[130 * 32];      // rows t0-1..t0+128, 64B rows
  __shared__ unsigned short Bs[3 * 128 * 32];  // [k][j_local][c], 64B rows

  f32x4 acc[4][4];
  #pragma unroll
  for (int i = 0; i < 4; i++)
    #pragma unroll
    for (int u = 0; u < 4; u++) acc[i][u] = (f32x4){0.f, 0.f, 0.f, 0.f};

  const unsigned short* xb = x + (size_t)b * TT * C;
  const int srow  = lane >> 2;   // row within a 16-row staging call
  const int sslot = lane & 3;    // 16B slot within 64B row
  const int rq = lane >> 4;      // frag chunk (8 bf16)
  const int rl = lane & 15;      // frag row

  for (int c0 = 0; c0 < C; c0 += 32) {
    __syncthreads();
    // ---- stage A rows 1..128 (t = t0 .. t0+127): 2 calls per wave, 16 rows each
    #pragma unroll
    for (int cc = 0; cc < 2; ++cc) {
      int lrow0 = 1 + wave * 32 + cc * 16;
      int lrow  = lrow0 + srow;
      int t = t0 + lrow - 1;
      int q = sslot ^ (lrow & 3);  // XOR-swizzled source chunk
      load_lds16(xb + (size_t)t * C + c0 + q * 8, &As[lrow0 * 32]);
    }
    // ---- stage B: 3 shifts x 128 rows = 384 rows: 6 calls per wave
    #pragma unroll
    for (int cc = 0; cc < 6; ++cc) {
      int R0 = (wave * 6 + cc) * 16;
      int R  = R0 + srow;
      int k = R >> 7;
      int j = R & 127;
      int q = sslot ^ (R & 3);
      load_lds16(wt + (size_t)k * (G3 * C) + (size_t)(j0 + j) * C + c0 + q * 8,
                 &Bs[R0 * 32]);
    }
    // ---- boundary rows lrow 0 (t0-1) and 129 (t0+128), zero-padded
    if (tid < 8) {
      int lr = (tid < 4) ? 0 : 129;
      int s  = tid & 3;
      int t  = t0 + lr - 1;
      int q  = s ^ (lr & 3);
      uint4 v = make_uint4(0, 0, 0, 0);
      if (t >= 0 && t < TT) v = *(const uint4*)(xb + (size_t)t * C + c0 + q * 8);
      *(uint4*)&As[lr * 32 + s * 8] = v;
    }
    __syncthreads();

    // ---- compute: 3 conv taps x 16 MFMA
    #pragma unroll
    for (int k = 0; k < 3; ++k) {
      bf16x8 af[4], bfr[4];
      #pragma unroll
      for (int im = 0; im < 4; ++im) {
        int lrow = wm * 64 + im * 16 + rl + k;
        af[im] = *(const bf16x8*)&As[lrow * 32 + ((rq ^ (lrow & 3)) * 8)];
      }
      #pragma unroll
      for (int in = 0; in < 4; ++in) {
        int R = k * 128 + wn * 64 + in * 16 + rl;
        bfr[in] = *(const bf16x8*)&Bs[R * 32 + ((rq ^ (R & 3)) * 8)];
      }
      #pragma unroll
      for (int im = 0; im < 4; ++im)
        #pragma unroll
        for (int in = 0; in < 4; ++in)
          acc[im][in] = __builtin_amdgcn_mfma_f32_16x16x32_bf16(
              af[im], bfr[in], acc[im][in], 0, 0, 0);
    }
  }

  // ---- epilogue: bias + activation (C/D: col=lane&15, row=quad*4+reg)
  const bool is_tanh = (j0 >= 2 * HDIM);  // j-tile never straddles a gate boundary
  const int row_in_tile = (lane >> 4) * 4;
  float* gb = g + (size_t)b * TT * G3;
  #pragma unroll
  for (int in = 0; in < 4; ++in) {
    int j = j0 + wn * 64 + in * 16 + rl;
    float bv = bias[j];
    #pragma unroll
    for (int im = 0; im < 4; ++im) {
      int tl = wm * 64 + im * 16 + row_in_tile;
      #pragma unroll
      for (int r = 0; r < 4; ++r) {
        float s = acc[im][in][r] + bv;
        float v;
        if (is_tanh) v = 1.f - 2.f / (__expf(2.f * s) + 1.f);
        else         v = 1.f / (1.f + __expf(-s));
        gb[(size_t)(t0 + tl + r) * G3 + j] = v;
      }
    }
  }
}

// ---------- chunked parallel fo-pool ----------
// P1: per-(b,h,chunk) affine summary: c_end = A*c_start + B over TC steps.
__global__ __launch_bounds__(256) void pool_chunk_kernel(
    const float* __restrict__ g, float* __restrict__ a_arr,
    float* __restrict__ b_arr, int dir)
{
  int idx = blockIdx.x * 256 + threadIdx.x;   // ch*8192 + b*1024 + h
  int h  = idx & (HDIM - 1);
  int b  = (idx >> 10) & (BB - 1);
  int ch = idx >> 13;
  const float* gb = g + (size_t)b * TT * G3 + h;
  float a = 1.f, bacc = 0.f;
  #pragma unroll 8
  for (int s = ch * TC; s < ch * TC + TC; ++s) {
    int t = dir ? (TT - 1 - s) : s;
    size_t go = (size_t)t * G3;
    float f = gb[go];
    float z = gb[go + 2 * HDIM];
    bacc = f * bacc + (1.f - f) * z;
    a *= f;
  }
  a_arr[idx] = a;
  b_arr[idx] = bacc;
}

// P2: serial scan over chunk summaries -> c at chunk starts.
__global__ __launch_bounds__(256) void pool_scan_kernel(
    const float* __restrict__ a_arr, const float* __restrict__ b_arr,
    float* __restrict__ cinit)
{
  int bh = blockIdx.x * 256 + threadIdx.x;   // 0 .. B*H-1
  float c = 0.f;
  #pragma unroll
  for (int ch = 0; ch < NCH; ++ch) {
    cinit[ch * (BB * HDIM) + bh] = c;
    c = a_arr[ch * (BB * HDIM) + bh] * c + b_arr[ch * (BB * HDIM) + bh];
  }
}

// P3: re-run recurrence per chunk from cinit; write h; record t==T-1 state.
template<int OUT_BF16>
__global__ __launch_bounds__(256) void pool_apply_kernel(
    const float* __restrict__ g, const float* __restrict__ cinit,
    void* __restrict__ out, float* __restrict__ hid, float* __restrict__ cell,
    int dir, int layer)
{
  int idx = blockIdx.x * 256 + threadIdx.x;
  int h  = idx & (HDIM - 1);
  int b  = (idx >> 10) & (BB - 1);
  int ch = idx >> 13;
  const float* gb = g + (size_t)b * TT * G3 + h;
  const int coloff = dir * HDIM;
  float c = cinit[idx];
  #pragma unroll 8
  for (int s = ch * TC; s < ch * TC + TC; ++s) {
    int t = dir ? (TT - 1 - s) : s;
    size_t go = (size_t)t * G3;
    float f = gb[go];
    float o = gb[go + HDIM];
    float z = gb[go + 2 * HDIM];
    c = f * c + (1.f - f) * z;
    float hv = c * o;
    size_t oo = ((size_t)b * TT + t) * (2 * HDIM) + coloff + h;
    if (OUT_BF16) ((unsigned short*)out)[oo] = f2bf(hv);
    else          ((float*)out)[oo] = hv;
    if (t == TT - 1) {   // fwd: last step; rev: first step (rcells[:,-1])
      size_t off = (size_t)layer * (BB * 2 * HDIM) + (size_t)b * (2 * HDIM) + coloff + h;
      hid[off] = hv;
      cell[off] = c;
    }
  }
}

extern "C" void kernel_launch(void* const* d_in, const int* in_sizes, int n_in,
                              void* d_out, int out_size, void* d_ws, size_t ws_size,
                              hipStream_t stream) {
  const float* x   = (const float*)d_in[0];
  const float* w0f = (const float*)d_in[2];
  const float* b0f = (const float*)d_in[3];
  const float* w0r = (const float*)d_in[4];
  const float* b0r = (const float*)d_in[5];
  const float* w1f = (const float*)d_in[6];
  const float* b1f = (const float*)d_in[7];
  const float* w1r = (const float*)d_in[8];
  const float* b1r = (const float*)d_in[9];

  float* out1 = (float*)d_out;                       // B*T*2H fp32
  float* hid  = out1 + (size_t)BB * TT * 2 * HDIM;   // 4*B*H
  float* cell = hid + 4 * BB * HDIM;                 // 4*B*H

  // workspace layout (byte offsets, all 16B aligned)
  char* ws = (char*)d_ws;
  size_t off = 0;
  float*          g     = (float*)(ws + off);  off += (size_t)BB * TT * G3 * 4;      // 100.7 MB
  unsigned short* out0b = (unsigned short*)(ws + off); off += (size_t)BB * TT * 2 * HDIM * 2; // 33.6 MB
  unsigned short* xb16  = (unsigned short*)(ws + off); off += (size_t)BB * TT * 1024 * 2;     // 16.8 MB
  unsigned short* wt    = (unsigned short*)(ws + off); off += (size_t)3 * G3 * 2048 * 2;      // 37.75 MB
  float* a_arr = (float*)(ws + off); off += (size_t)NCH * BB * HDIM * 4;  // 1 MB
  float* b_arr = (float*)(ws + off); off += (size_t)NCH * BB * HDIM * 4;  // 1 MB
  float* cinit = (float*)(ws + off); off += (size_t)NCH * BB * HDIM * 4;  // 1 MB

  dim3 blk(256);
  dim3 cgrd(TT / 128, G3 / 128, BB);          // (8, 24, 8)
  dim3 chgrd(NCH * BB * HDIM / 256);          // 1024
  dim3 scgrd(BB * HDIM / 256);                // 32

  // x -> bf16
  int nx = BB * TT * 1024;
  cvt_x_kernel<<<nx / (256 * 4), blk, 0, stream>>>(x, xb16, nx);

  #define RUN_POOL(OUTB, outp, dir, layer)                                         \
    pool_chunk_kernel<<<chgrd, blk, 0, stream>>>(g, a_arr, b_arr, dir);            \
    pool_scan_kernel<<<scgrd, blk, 0, stream>>>(a_arr, b_arr, cinit);              \
    pool_apply_kernel<OUTB><<<chgrd, blk, 0, stream>>>(g, cinit, outp, hid, cell,  \
                                                       dir, layer);

  // ---- layer 0 (C=1024)
  cvt_w_kernel<1024><<<3 * G3 * 1024 / 256, blk, 0, stream>>>(w0f, wt);
  conv_mfma_kernel<1024><<<cgrd, blk, 0, stream>>>(xb16, wt, b0f, g);
  RUN_POOL(1, out0b, 0, 0)

  cvt_w_kernel<1024><<<3 * G3 * 1024 / 256, blk, 0, stream>>>(w0r, wt);
  conv_mfma_kernel<1024><<<cgrd, blk, 0, stream>>>(xb16, wt, b0r, g);
  RUN_POOL(1, out0b, 1, 0)

  // ---- layer 1 (C=2048)
  cvt_w_kernel<2048><<<3 * G3 * 2048 / 256, blk, 0, stream>>>(w1f, wt);
  conv_mfma_kernel<2048><<<cgrd, blk, 0, stream>>>(out0b, wt, b1f, g);
  RUN_POOL(0, out1, 0, 1)

  cvt_w_kernel<2048><<<3 * G3 * 2048 / 256, blk, 0, stream>>>(w1r, wt);
  conv_mfma_kernel<2048><<<cgrd, blk, 0, stream>>>(out0b, wt, b1r, g);
  RUN_POOL(0, out1, 1, 1)
  #undef RUN_POOL
}

// Round 4
// 1350.192 us; speedup vs baseline: 13.3330x; 1.0888x over previous
//
#include <hip/hip_runtime.h>
#include <math.h>

#define BB 8
#define TT 1024
#define HDIM 1024
#define G3 3072   // 3*H
#define NCH 32    // scan chunks
#define TC 32     // steps per chunk (NCH*TC == TT)

// bank-group swizzle: chunk q of row r lives at 16B-slot (q ^ SW(r)) within the row.
// SW must depend on r>>1 (not r&1-correlated bits) so (r&1, q') covers all 8
// 16B bank-groups across 8 consecutive rows -> 2-way (free) instead of 4-way.
#define SW(r) (((r) >> 1) & 3)

typedef __attribute__((ext_vector_type(8))) short bf16x8;   // 8 bf16 = 4 VGPRs
typedef __attribute__((ext_vector_type(4))) float f32x4;

__device__ __forceinline__ unsigned short f2bf(float f) {
  union { float f; unsigned int u; } c; c.f = f;
  unsigned int u = c.u;
  return (unsigned short)((u + 0x7FFFu + ((u >> 16) & 1u)) >> 16);
}

__device__ __forceinline__ void load_lds16(const void* g, void* l) {
  __builtin_amdgcn_global_load_lds(
      (const __attribute__((address_space(1))) void*)g,
      (__attribute__((address_space(3))) void*)l, 16, 0, 0);
}

// x [B,T,D] fp32 -> bf16
__global__ __launch_bounds__(256) void cvt_x_kernel(const float* __restrict__ in,
                                                    unsigned short* __restrict__ out, int n) {
  int i = (blockIdx.x * 256 + threadIdx.x) * 4;
  if (i >= n) return;
  float4 v = *(const float4*)(in + i);
  ushort4 o;
  o.x = f2bf(v.x); o.y = f2bf(v.y); o.z = f2bf(v.z); o.w = f2bf(v.w);
  *(ushort4*)(out + i) = o;
}

// w [3H, C, 3] fp32 -> wt [3][3H][C] bf16
template<int C>
__global__ __launch_bounds__(256) void cvt_w_kernel(const float* __restrict__ in,
                                                    unsigned short* __restrict__ out) {
  int o = blockIdx.x * 256 + threadIdx.x;  // 3*3072*C total
  int c = o & (C - 1);
  int jk = o / C;
  int j = jk % G3;
  int k = jk / G3;
  out[o] = f2bf(in[(size_t)j * (3 * C) + (size_t)c * 3 + k]);
}

// conv-gates via bf16 MFMA: g[b,t,j] = act(bias[j] + sum_{k,c} wt[k][j][c]*x[b,t+k-1,c])
// 1-D grid of 1536 blocks, XCD-aware remap: xcd = L&7 owns j-tiles 3*xcd..3*xcd+2
// for all (t,b) -> per-XCD L2 weight working set 2.4/4.7 MB instead of 37.7 MB.
// Block: 128(t) x 128(j), BK=32. 4 waves, each 64x64 via 4x4 mfma 16x16x32.
template<int C>
__global__ __launch_bounds__(256) void conv_mfma_kernel(
    const unsigned short* __restrict__ x,   // [B,T,C] bf16
    const unsigned short* __restrict__ wt,  // [3][3072][C] bf16
    const float* __restrict__ bias,         // [3072]
    float* __restrict__ g)                  // [B,T,3072]
{
  const int L    = blockIdx.x;
  const int xcd  = L & 7;
  const int sL   = L >> 3;
  const int jt   = xcd * 3 + (sL % 3);
  const int rest = sL / 3;          // 0..63
  const int t0 = (rest & 7) * 128;
  const int j0 = jt * 128;
  const int b  = rest >> 3;

  const int tid  = threadIdx.x;
  const int lane = tid & 63;
  const int wave = tid >> 6;
  const int wm = wave >> 1, wn = wave & 1;

  __shared__ unsigned short As[130 * 32];      // rows t0-1..t0+128, 64B rows
  __shared__ unsigned short Bs[3 * 128 * 32];  // [k][j_local][c], 64B rows

  f32x4 acc[4][4];
  #pragma unroll
  for (int i = 0; i < 4; i++)
    #pragma unroll
    for (int u = 0; u < 4; u++) acc[i][u] = (f32x4){0.f, 0.f, 0.f, 0.f};

  const unsigned short* xb = x + (size_t)b * TT * C;
  const int srow  = lane >> 2;   // row within a 16-row staging call
  const int sslot = lane & 3;    // 16B slot within 64B row
  const int rq = lane >> 4;      // frag chunk (8 bf16)
  const int rl = lane & 15;      // frag row

  for (int c0 = 0; c0 < C; c0 += 32) {
    __syncthreads();
    // ---- stage A rows 1..128 (t = t0 .. t0+127): 2 calls per wave, 16 rows each
    #pragma unroll
    for (int cc = 0; cc < 2; ++cc) {
      int lrow0 = 1 + wave * 32 + cc * 16;
      int lrow  = lrow0 + srow;
      int t = t0 + lrow - 1;
      int q = sslot ^ SW(lrow);    // slot sslot holds memory chunk q
      load_lds16(xb + (size_t)t * C + c0 + q * 8, &As[lrow0 * 32]);
    }
    // ---- stage B: 3 shifts x 128 rows = 384 rows: 6 calls per wave
    #pragma unroll
    for (int cc = 0; cc < 6; ++cc) {
      int R0 = (wave * 6 + cc) * 16;
      int R  = R0 + srow;
      int k = R >> 7;
      int j = R & 127;
      int q = sslot ^ SW(R);
      load_lds16(wt + (size_t)k * (G3 * C) + (size_t)(j0 + j) * C + c0 + q * 8,
                 &Bs[R0 * 32]);
    }
    // ---- boundary rows lrow 0 (t0-1) and 129 (t0+128), zero-padded
    if (tid < 8) {
      int lr = (tid < 4) ? 0 : 129;
      int s  = tid & 3;
      int t  = t0 + lr - 1;
      int q  = s ^ SW(lr);
      uint4 v = make_uint4(0, 0, 0, 0);
      if (t >= 0 && t < TT) v = *(const uint4*)(xb + (size_t)t * C + c0 + q * 8);
      *(uint4*)&As[lr * 32 + s * 8] = v;
    }
    __syncthreads();

    // ---- compute: 3 conv taps x 16 MFMA
    #pragma unroll
    for (int k = 0; k < 3; ++k) {
      bf16x8 af[4], bfr[4];
      #pragma unroll
      for (int im = 0; im < 4; ++im) {
        int lrow = wm * 64 + im * 16 + rl + k;
        af[im] = *(const bf16x8*)&As[lrow * 32 + ((rq ^ SW(lrow)) * 8)];
      }
      #pragma unroll
      for (int in = 0; in < 4; ++in) {
        int R = k * 128 + wn * 64 + in * 16 + rl;
        bfr[in] = *(const bf16x8*)&Bs[R * 32 + ((rq ^ SW(R)) * 8)];
      }
      #pragma unroll
      for (int im = 0; im < 4; ++im)
        #pragma unroll
        for (int in = 0; in < 4; ++in)
          acc[im][in] = __builtin_amdgcn_mfma_f32_16x16x32_bf16(
              af[im], bfr[in], acc[im][in], 0, 0, 0);
    }
  }

  // ---- epilogue: bias + activation (C/D: col=lane&15, row=quad*4+reg)
  const bool is_tanh = (j0 >= 2 * HDIM);  // j-tile never straddles a gate boundary
  const int row_in_tile = (lane >> 4) * 4;
  float* gb = g + (size_t)b * TT * G3;
  #pragma unroll
  for (int in = 0; in < 4; ++in) {
    int j = j0 + wn * 64 + in * 16 + rl;
    float bv = bias[j];
    #pragma unroll
    for (int im = 0; im < 4; ++im) {
      int tl = wm * 64 + im * 16 + row_in_tile;
      #pragma unroll
      for (int r = 0; r < 4; ++r) {
        float s = acc[im][in][r] + bv;
        float v;
        if (is_tanh) v = 1.f - 2.f / (__expf(2.f * s) + 1.f);
        else         v = 1.f / (1.f + __expf(-s));
        gb[(size_t)(t0 + tl + r) * G3 + j] = v;
      }
    }
  }
}

// ---------- chunked parallel fo-pool ----------
// P1: per-(b,h,chunk) affine summary: c_end = A*c_start + B over TC steps.
__global__ __launch_bounds__(256) void pool_chunk_kernel(
    const float* __restrict__ g, float* __restrict__ a_arr,
    float* __restrict__ b_arr, int dir)
{
  int idx = blockIdx.x * 256 + threadIdx.x;   // ch*8192 + b*1024 + h
  int h  = idx & (HDIM - 1);
  int b  = (idx >> 10) & (BB - 1);
  int ch = idx >> 13;
  const float* gb = g + (size_t)b * TT * G3 + h;
  float a = 1.f, bacc = 0.f;
  #pragma unroll 8
  for (int s = ch * TC; s < ch * TC + TC; ++s) {
    int t = dir ? (TT - 1 - s) : s;
    size_t go = (size_t)t * G3;
    float f = gb[go];
    float z = gb[go + 2 * HDIM];
    bacc = f * bacc + (1.f - f) * z;
    a *= f;
  }
  a_arr[idx] = a;
  b_arr[idx] = bacc;
}

// P2: serial scan over chunk summaries -> c at chunk starts.
__global__ __launch_bounds__(256) void pool_scan_kernel(
    const float* __restrict__ a_arr, const float* __restrict__ b_arr,
    float* __restrict__ cinit)
{
  int bh = blockIdx.x * 256 + threadIdx.x;   // 0 .. B*H-1
  float c = 0.f;
  #pragma unroll
  for (int ch = 0; ch < NCH; ++ch) {
    cinit[ch * (BB * HDIM) + bh] = c;
    c = a_arr[ch * (BB * HDIM) + bh] * c + b_arr[ch * (BB * HDIM) + bh];
  }
}

// P3: re-run recurrence per chunk from cinit; write h; record t==T-1 state.
template<int OUT_BF16>
__global__ __launch_bounds__(256) void pool_apply_kernel(
    const float* __restrict__ g, const float* __restrict__ cinit,
    void* __restrict__ out, float* __restrict__ hid, float* __restrict__ cell,
    int dir, int layer)
{
  int idx = blockIdx.x * 256 + threadIdx.x;
  int h  = idx & (HDIM - 1);
  int b  = (idx >> 10) & (BB - 1);
  int ch = idx >> 13;
  const float* gb = g + (size_t)b * TT * G3 + h;
  const int coloff = dir * HDIM;
  float c = cinit[idx];
  #pragma unroll 8
  for (int s = ch * TC; s < ch * TC + TC; ++s) {
    int t = dir ? (TT - 1 - s) : s;
    size_t go = (size_t)t * G3;
    float f = gb[go];
    float o = gb[go + HDIM];
    float z = gb[go + 2 * HDIM];
    c = f * c + (1.f - f) * z;
    float hv = c * o;
    size_t oo = ((size_t)b * TT + t) * (2 * HDIM) + coloff + h;
    if (OUT_BF16) ((unsigned short*)out)[oo] = f2bf(hv);
    else          ((float*)out)[oo] = hv;
    if (t == TT - 1) {   // fwd: last step; rev: first step (rcells[:,-1])
      size_t off = (size_t)layer * (BB * 2 * HDIM) + (size_t)b * (2 * HDIM) + coloff + h;
      hid[off] = hv;
      cell[off] = c;
    }
  }
}

extern "C" void kernel_launch(void* const* d_in, const int* in_sizes, int n_in,
                              void* d_out, int out_size, void* d_ws, size_t ws_size,
                              hipStream_t stream) {
  const float* x   = (const float*)d_in[0];
  const float* w0f = (const float*)d_in[2];
  const float* b0f = (const float*)d_in[3];
  const float* w0r = (const float*)d_in[4];
  const float* b0r = (const float*)d_in[5];
  const float* w1f = (const float*)d_in[6];
  const float* b1f = (const float*)d_in[7];
  const float* w1r = (const float*)d_in[8];
  const float* b1r = (const float*)d_in[9];

  float* out1 = (float*)d_out;                       // B*T*2H fp32
  float* hid  = out1 + (size_t)BB * TT * 2 * HDIM;   // 4*B*H
  float* cell = hid + 4 * BB * HDIM;                 // 4*B*H

  // workspace layout (byte offsets, all 16B aligned)
  char* ws = (char*)d_ws;
  size_t off = 0;
  float*          g     = (float*)(ws + off);  off += (size_t)BB * TT * G3 * 4;      // 100.7 MB
  unsigned short* out0b = (unsigned short*)(ws + off); off += (size_t)BB * TT * 2 * HDIM * 2; // 33.6 MB
  unsigned short* xb16  = (unsigned short*)(ws + off); off += (size_t)BB * TT * 1024 * 2;     // 16.8 MB
  unsigned short* wt    = (unsigned short*)(ws + off); off += (size_t)3 * G3 * 2048 * 2;      // 37.75 MB
  float* a_arr = (float*)(ws + off); off += (size_t)NCH * BB * HDIM * 4;  // 1 MB
  float* b_arr = (float*)(ws + off); off += (size_t)NCH * BB * HDIM * 4;  // 1 MB
  float* cinit = (float*)(ws + off); off += (size_t)NCH * BB * HDIM * 4;  // 1 MB

  dim3 blk(256);
  dim3 cgrd(8 * 24 * 8);                      // 1536, 1-D; XCD remap inside
  dim3 chgrd(NCH * BB * HDIM / 256);          // 1024
  dim3 scgrd(BB * HDIM / 256);                // 32

  // x -> bf16
  int nx = BB * TT * 1024;
  cvt_x_kernel<<<nx / (256 * 4), blk, 0, stream>>>(x, xb16, nx);

  #define RUN_POOL(OUTB, outp, dir, layer)                                         \
    pool_chunk_kernel<<<chgrd, blk, 0, stream>>>(g, a_arr, b_arr, dir);            \
    pool_scan_kernel<<<scgrd, blk, 0, stream>>>(a_arr, b_arr, cinit);              \
    pool_apply_kernel<OUTB><<<chgrd, blk, 0, stream>>>(g, cinit, outp, hid, cell,  \
                                                       dir, layer);

  // ---- layer 0 (C=1024)
  cvt_w_kernel<1024><<<3 * G3 * 1024 / 256, blk, 0, stream>>>(w0f, wt);
  conv_mfma_kernel<1024><<<cgrd, blk, 0, stream>>>(xb16, wt, b0f, g);
  RUN_POOL(1, out0b, 0, 0)

  cvt_w_kernel<1024><<<3 * G3 * 1024 / 256, blk, 0, stream>>>(w0r, wt);
  conv_mfma_kernel<1024><<<cgrd, blk, 0, stream>>>(xb16, wt, b0r, g);
  RUN_POOL(1, out0b, 1, 0)

  // ---- layer 1 (C=2048)
  cvt_w_kernel<2048><<<3 * G3 * 2048 / 256, blk, 0, stream>>>(w1f, wt);
  conv_mfma_kernel<2048><<<cgrd, blk, 0, stream>>>(out0b, wt, b1f, g);
  RUN_POOL(0, out1, 0, 1)

  cvt_w_kernel<2048><<<3 * G3 * 2048 / 256, blk, 0, stream>>>(w1r, wt);
  conv_mfma_kernel<2048><<<cgrd, blk, 0, stream>>>(out0b, wt, b1r, g);
  RUN_POOL(0, out1, 1, 1)
  #undef RUN_POOL
}